// Round 7
// baseline (651.682 us; speedup 1.0000x reference)
//
#include <hip/hip_runtime.h>
#include <hip/hip_cooperative_groups.h>
#include <math.h>

namespace cg = cooperative_groups;

#define B 8
#define C 256
#define H 160
#define W 160
#define HW (H*W)
#define HIDDEN 16

#define CCHUNK 32               // channels per k1 block
#define NCHUNK (C/CCHUNK)       // 8 channel chunks
#define GRP 4                   // channels per butterfly batch (reg-pressure cap)
#define W4 (W/4)                // 40 float4 per row
#define F4B (HW/4)              // 6400 float4 per (b,c) plane
#define PBB (F4B/256)           // 25 pixel-blocks per batch
#define PBLKS (B*PBB)           // 200 pixel-blocks total
#define FOLDU ((B*4*F4B)/256)   // 800 fold units (256 thr each)
#define K3U   ((B*F4B)/256)     // 200 conv units (256 thr, 4px/thread)
#define GRIDB 512               // cooperative grid (2 blocks/CU guaranteed)
#define TOTF4 (B*C*HW/4)        // 13,107,200 float4 in x/out
#define K4IT  (TOTF4/(GRIDB*256)) // 100 combine iters/thread

typedef float vf4 __attribute__((ext_vector_type(4)));

// Separable Sobel core: columns s = t+2m+b (smooth), d = t-b (diff);
// gx[i] = s[i]-s[i+2], gy[i] = d[i]+2d[i+1]+d[i+2]. 0.25 and eps folded.
__device__ __forceinline__ float sobel4_sep(
    float tl, float4 t4, float tr,
    float ml, float4 m4, float mr,
    float bl, float4 b4, float br,
    float4& sum_x, float4& max_x, float4& sum_g, float4& max_g)
{
    float s0 = fmaf(2.f, ml,   tl)   + bl;
    float s1 = fmaf(2.f, m4.x, t4.x) + b4.x;
    float s2 = fmaf(2.f, m4.y, t4.y) + b4.y;
    float s3 = fmaf(2.f, m4.z, t4.z) + b4.z;
    float s4 = fmaf(2.f, m4.w, t4.w) + b4.w;
    float s5 = fmaf(2.f, mr,   tr)   + br;
    float d0 = tl   - bl;
    float d1 = t4.x - b4.x;
    float d2 = t4.y - b4.y;
    float d3 = t4.z - b4.z;
    float d4 = t4.w - b4.w;
    float d5 = tr   - br;

    float g0, g1, g2, g3;
    { float u = s0 - s2, v = fmaf(2.f, d1, d0) + d2;
      g0 = 0.25f * __builtin_amdgcn_sqrtf(fmaf(v, v, fmaf(u, u, 1.6e-11f))); }
    { float u = s1 - s3, v = fmaf(2.f, d2, d1) + d3;
      g1 = 0.25f * __builtin_amdgcn_sqrtf(fmaf(v, v, fmaf(u, u, 1.6e-11f))); }
    { float u = s2 - s4, v = fmaf(2.f, d3, d2) + d4;
      g2 = 0.25f * __builtin_amdgcn_sqrtf(fmaf(v, v, fmaf(u, u, 1.6e-11f))); }
    { float u = s3 - s5, v = fmaf(2.f, d4, d3) + d5;
      g3 = 0.25f * __builtin_amdgcn_sqrtf(fmaf(v, v, fmaf(u, u, 1.6e-11f))); }

    sum_x.x += m4.x; sum_x.y += m4.y; sum_x.z += m4.z; sum_x.w += m4.w;
    max_x.x = fmaxf(max_x.x, m4.x); max_x.y = fmaxf(max_x.y, m4.y);
    max_x.z = fmaxf(max_x.z, m4.z); max_x.w = fmaxf(max_x.w, m4.w);
    sum_g.x += g0; sum_g.y += g1; sum_g.z += g2; sum_g.w += g3;
    max_g.x = fmaxf(max_g.x, g0); max_g.y = fmaxf(max_g.y, g1);
    max_g.z = fmaxf(max_g.z, g2); max_g.w = fmaxf(max_g.w, g3);
    return (g0+g1) + (g2+g3);
}

// ---------------- k1: Sobel + partial reductions (unchanged from R6) ----------------
__global__ __launch_bounds__(256) void k1_sobel_stats(
    const float* __restrict__ x, float* __restrict__ part_c,
    float* __restrict__ part_s)
{
    const int tid   = threadIdx.x;
    const int blk   = blockIdx.x;
    const int chunk = blk & (NCHUNK-1);
    const int pblk  = blk >> 3;                 // [0, PBLKS)
    const int f     = pblk * 256 + tid;         // global float4 index
    const int b     = f / F4B;
    const int r     = f % F4B;
    const int h     = r / W4;
    const int w     = (r % W4) * 4;             // leftmost of 4 pixels
    const int hw    = h * W + w;

    const bool up = (h > 0), dn = (h < H-1), lf = (w > 0), rt = (w+4 < W);
    const float lff = lf ? 1.f : 0.f, rtf = rt ? 1.f : 0.f;

    const float* xp = x + (size_t)(b*C + chunk*CCHUNK) * HW + hw;
    float* pcw = part_c + ((size_t)blk*4 + (tid >> 6)) * CCHUNK;

    float4 sum_x = {0,0,0,0}, sum_g = {0,0,0,0};
    float4 max_x = {-INFINITY,-INFINITY,-INFINITY,-INFINITY};
    float4 max_g = {-INFINITY,-INFINITY,-INFINITY,-INFINITY};

    if (__all(up && dn)) {
        #pragma unroll 1
        for (int grp = 0; grp < CCHUNK/GRP; ++grp) {
            float gs[GRP];
            #pragma unroll
            for (int u = 0; u < GRP; ++u) {
                const float* q = xp + (size_t)(grp*GRP + u) * HW;
                float4 t4 = *(const float4*)(q - W);
                float4 m4 = *(const float4*)(q);
                float4 b4 = *(const float4*)(q + W);
                float tl = q[-W-1]*lff, tr = q[-W+4]*rtf;
                float ml = q[-1]  *lff, mr = q[4]   *rtf;
                float bl = q[W-1] *lff, br = q[W+4] *rtf;
                gs[u] = sobel4_sep(tl,t4,tr, ml,m4,mr, bl,b4,br,
                                   sum_x, max_x, sum_g, max_g);
            }
            #pragma unroll
            for (int off = 32; off; off >>= 1) {
                #pragma unroll
                for (int u = 0; u < GRP; ++u)
                    gs[u] += __shfl_xor(gs[u], off, 64);
            }
            if ((tid & 63) == 0) {
                float4 v0 = { gs[0], gs[1], gs[2], gs[3] };
                *(float4*)(pcw + grp*GRP) = v0;
            }
        }
    } else {
        const float upf = up ? 1.f : 0.f, dnf = dn ? 1.f : 0.f;
        const float f_tl = upf*lff, f_tr = upf*rtf;
        const float f_bl = dnf*lff, f_br = dnf*rtf;
        const int ot = up ? -W : 0;
        const int ob = dn ?  W : 0;
        const int ol = lf ? -1 : 0;
        const int orr= rt ?  4 : 3;

        #pragma unroll 1
        for (int grp = 0; grp < CCHUNK/GRP; ++grp) {
            float gs[GRP];
            #pragma unroll
            for (int u = 0; u < GRP; ++u) {
                const float* q = xp + (size_t)(grp*GRP + u) * HW;
                float4 t4 = *(const float4*)(q + ot);
                float4 m4 = *(const float4*)(q);
                float4 b4 = *(const float4*)(q + ob);
                float tl = q[ot+ol]*f_tl, tr = q[ot+orr]*f_tr;
                float ml = q[ol]  *lff,   mr = q[orr]  *rtf;
                float bl = q[ob+ol]*f_bl, br = q[ob+orr]*f_br;
                t4.x*=upf; t4.y*=upf; t4.z*=upf; t4.w*=upf;
                b4.x*=dnf; b4.y*=dnf; b4.z*=dnf; b4.w*=dnf;
                gs[u] = sobel4_sep(tl,t4,tr, ml,m4,mr, bl,b4,br,
                                   sum_x, max_x, sum_g, max_g);
            }
            #pragma unroll
            for (int off = 32; off; off >>= 1) {
                #pragma unroll
                for (int u = 0; u < GRP; ++u)
                    gs[u] += __shfl_xor(gs[u], off, 64);
            }
            if ((tid & 63) == 0) {
                float4 v0 = { gs[0], gs[1], gs[2], gs[3] };
                *(float4*)(pcw + grp*GRP) = v0;
            }
        }
    }

    float* sp = part_s + (size_t)(chunk*B + b) * 4 * HW + hw;
    *(float4*)(sp)        = sum_x;
    *(float4*)(sp +   HW) = max_x;
    *(float4*)(sp + 2*HW) = sum_g;
    *(float4*)(sp + 3*HW) = max_g;
}

// ---------------- shared device helpers for fold / mlp / conv / combine ----------------
__device__ __forceinline__ void fold_unit(int u, int tid,
    const float* __restrict__ part_s, float* __restrict__ s_in)
{
    const int g    = u * 256 + tid;              // [0, B*4*F4B)
    const int b    = g / (4*F4B);
    const int rr   = g % (4*F4B);
    const int plane= rr / F4B;
    const int hw   = (rr % F4B) * 4;

    const float* sp0 = part_s + (size_t)b * 4 * HW + plane*HW + hw;
    const size_t cstride = (size_t)B * 4 * HW;

    float4 v = *(const float4*)(sp0);
    if (plane == 0 || plane == 2) {
        #pragma unroll
        for (int c = 1; c < NCHUNK; ++c) {
            float4 uu = *(const float4*)(sp0 + c*cstride);
            v.x += uu.x; v.y += uu.y; v.z += uu.z; v.w += uu.w;
        }
        v.x *= (1.f/C); v.y *= (1.f/C); v.z *= (1.f/C); v.w *= (1.f/C);
    } else {
        #pragma unroll
        for (int c = 1; c < NCHUNK; ++c) {
            float4 uu = *(const float4*)(sp0 + c*cstride);
            v.x = fmaxf(v.x,uu.x); v.y = fmaxf(v.y,uu.y);
            v.z = fmaxf(v.z,uu.z); v.w = fmaxf(v.w,uu.w);
        }
    }
    *(float4*)(s_in + (size_t)b * 4 * HW + plane*HW + hw) = v;
}

__device__ __forceinline__ void mlp_block(int b, int tid,
    const float* __restrict__ part_c, const float* __restrict__ w1,
    const float* __restrict__ w2, const float* __restrict__ beta,
    float* __restrict__ chanfac, float* cv, float* hb)
{
    const int chunk = tid >> 5;            // CCHUNK=32
    const int cc    = tid & (CCHUNK-1);

    float acc = 0.f;
    for (int pbb = 0; pbb < PBB; ++pbb) {
        const int blk = (b*PBB + pbb) * NCHUNK + chunk;
        const float* pcb = part_c + (size_t)blk * 4 * CCHUNK + cc;
        acc += (pcb[0] + pcb[CCHUNK]) + (pcb[2*CCHUNK] + pcb[3*CCHUNK]);
    }
    cv[tid] = acc * (1.f/(float)HW);
    __syncthreads();

    if (tid < HIDDEN) {
        float a = 0.f;
        for (int c = 0; c < C; ++c) a += cv[c] * w1[tid*C + c];
        hb[tid] = fmaxf(a, 0.f);
    }
    __syncthreads();

    float bt = beta[0];
    float sb = (bt > 20.f) ? bt : log1pf(expf(bt));   // softplus
    float a = 0.f;
    #pragma unroll
    for (int j = 0; j < HIDDEN; ++j) a += hb[j] * w2[tid*HIDDEN + j];
    float gate = 1.f / (1.f + expf(-a));
    chanfac[b*C + tid] = 1.f + sb * gate;
}

__device__ __forceinline__ void conv_unit(int p4,
    const float* __restrict__ s_in, const float* wgt,
    float bias, float sa, float* __restrict__ sfac)
{
    const int b  = p4 / F4B;
    const int r  = p4 % F4B;
    const int h  = r / W4;
    const int w  = (r % W4) * 4;

    float wmk[11];                            // col masks for rb[1..10]
    #pragma unroll
    for (int k = 1; k <= 10; ++k) {
        int col = w - 4 + k;
        wmk[k] = (col >= 0 && col < W) ? 1.f : 0.f;
    }
    int hc[7]; float hm[7];
    #pragma unroll
    for (int i = 0; i < 7; ++i) {
        int hh = h + i - 3;
        hm[i] = (hh >= 0 && hh < H) ? 1.f : 0.f;
        hc[i] = min(max(hh, 0), H-1);
    }
    const int loff = (w >= 4)    ? -4 : 0;    // clamped: masked anyway at w==0
    const int roff = (w + 4 < W) ?  4 : 0;    // clamped: masked anyway at w==W-4

    const float* base = s_in + (size_t)b * 4 * HW + w;
    float a0=0.f, a1=0.f, a2=0.f, a3=0.f;
    #pragma unroll
    for (int ci = 0; ci < 4; ++ci) {
        const float* pl = base + ci*HW;
        #pragma unroll
        for (int i = 0; i < 7; ++i) {
            const float* rp = pl + hc[i]*W;
            float4 L  = *(const float4*)(rp + loff);
            float4 Mv = *(const float4*)(rp);
            float4 R  = *(const float4*)(rp + roff);
            float rb[12] = { L.x,L.y,L.z,L.w, Mv.x,Mv.y,Mv.z,Mv.w, R.x,R.y,R.z,R.w };
            #pragma unroll
            for (int k = 1; k <= 10; ++k) rb[k] *= wmk[k];
            const float* wr = wgt + ci*49 + i*7;
            float r0=0.f, r1=0.f, r2=0.f, r3=0.f;
            #pragma unroll
            for (int j = 0; j < 7; ++j) {
                float wj = wr[j];
                r0 = fmaf(wj, rb[j+1], r0);
                r1 = fmaf(wj, rb[j+2], r1);
                r2 = fmaf(wj, rb[j+3], r2);
                r3 = fmaf(wj, rb[j+4], r3);
            }
            a0 = fmaf(r0, hm[i], a0);
            a1 = fmaf(r1, hm[i], a1);
            a2 = fmaf(r2, hm[i], a2);
            a3 = fmaf(r3, hm[i], a3);
        }
    }
    float4 o;
    o.x = 1.f + sa / (1.f + expf(-(a0 + bias)));
    o.y = 1.f + sa / (1.f + expf(-(a1 + bias)));
    o.z = 1.f + sa / (1.f + expf(-(a2 + bias)));
    o.w = 1.f + sa / (1.f + expf(-(a3 + bias)));
    *(float4*)(sfac + (size_t)b * HW + h*W + w) = o;
}

// ---------------- k_rest: fold+MLP -> gridsync -> conv -> gridsync -> combine ----------
__global__ __launch_bounds__(256) void k_rest(
    const float* __restrict__ x, const float* __restrict__ part_s,
    const float* __restrict__ part_c, const float* __restrict__ w1,
    const float* __restrict__ w2, const float* __restrict__ beta,
    const float* __restrict__ sw, const float* __restrict__ sbias,
    const float* __restrict__ alpha,
    float* __restrict__ s_in, float* __restrict__ sfac,
    float* __restrict__ chanfac, float* __restrict__ out)
{
    __shared__ float cv[C];
    __shared__ float hb[HIDDEN];
    __shared__ float wgt[4*49];
    const int tid = threadIdx.x;
    const int bid = blockIdx.x;
    cg::grid_group grid = cg::this_grid();

    // ---- phase A: fold s_in (800 units) + channel MLP (last 8 blocks) ----
    for (int u = bid; u < FOLDU; u += GRIDB)
        fold_unit(u, tid, part_s, s_in);
    if (bid >= GRIDB - B)
        mlp_block(bid - (GRIDB - B), tid, part_c, w1, w2, beta, chanfac, cv, hb);

    __threadfence();
    grid.sync();

    // ---- phase B: 7x7 conv -> sfac (200 units) ----
    if (bid < K3U) {
        for (int k = tid; k < 196; k += 256) wgt[k] = sw[k];
        __syncthreads();
        float al = alpha[0];
        float sa = (al > 20.f) ? al : log1pf(expf(al));   // softplus
        conv_unit(bid*256 + tid, s_in, wgt, sbias[0], sa, sfac);
    }

    __threadfence();
    grid.sync();

    // ---- phase C: combine, grid-strided, nontemporal streaming ----
    const vf4* x4 = (const vf4*)x;
    vf4* out4 = (vf4*)out;
    #pragma unroll 1
    for (int k = 0; k < K4IT; ++k) {
        const int i  = k*(GRIDB*256) + bid*256 + tid;   // float4 index
        const int bc = i / (HW/4);       // b*C + c
        const int hw = (i % (HW/4)) * 4;
        const int b  = bc >> 8;          // /C

        const float cf = chanfac[bc];
        const float4 s = *(const float4*)&sfac[b*HW + hw];
        vf4 xv = __builtin_nontemporal_load(&x4[i]);
        vf4 o;
        o.x = xv.x * s.x * cf;
        o.y = xv.y * s.y * cf;
        o.z = xv.z * s.z * cf;
        o.w = xv.w * s.w * cf;
        __builtin_nontemporal_store(o, &out4[i]);
    }
}

// ---------------- fallback kernels (non-cooperative path) ----------------
__global__ __launch_bounds__(256) void k1b_fold_mlp(
    const float* __restrict__ part_s, float* __restrict__ s_in,
    const float* __restrict__ part_c, const float* __restrict__ w1,
    const float* __restrict__ w2, const float* __restrict__ beta,
    float* __restrict__ chanfac)
{
    __shared__ float cv[C];
    __shared__ float hb[HIDDEN];
    const int tid = threadIdx.x;
    if (blockIdx.x < FOLDU) { fold_unit(blockIdx.x, tid, part_s, s_in); return; }
    mlp_block(blockIdx.x - FOLDU, tid, part_c, w1, w2, beta, chanfac, cv, hb);
}

__global__ __launch_bounds__(256) void k3_spatial(
    const float* __restrict__ s_in, const float* __restrict__ sw,
    const float* __restrict__ sbias, const float* __restrict__ alpha,
    float* __restrict__ sfac)
{
    __shared__ float wgt[4*49];
    const int tid = threadIdx.x;
    for (int k = tid; k < 196; k += 256) wgt[k] = sw[k];
    __syncthreads();
    float al = alpha[0];
    float sa = (al > 20.f) ? al : log1pf(expf(al));
    conv_unit(blockIdx.x*256 + tid, s_in, wgt, sbias[0], sa, sfac);
}

__global__ __launch_bounds__(256) void k4_combine(
    const float* __restrict__ x, const float* __restrict__ sfac,
    const float* __restrict__ chanfac, float* __restrict__ out)
{
    const vf4* x4 = (const vf4*)x;
    vf4* out4 = (vf4*)out;
    const int i0 = blockIdx.x * 512 + threadIdx.x;
    #pragma unroll
    for (int k = 0; k < 2; ++k) {
        const int i  = i0 + k*256;
        const int bc = i / (HW/4);
        const int hw = (i % (HW/4)) * 4;
        const int b  = bc >> 8;
        const float cf = chanfac[bc];
        const float4 s = *(const float4*)&sfac[b*HW + hw];
        vf4 xv = __builtin_nontemporal_load(&x4[i]);
        vf4 o;
        o.x = xv.x * s.x * cf;
        o.y = xv.y * s.y * cf;
        o.z = xv.z * s.z * cf;
        o.w = xv.w * s.w * cf;
        __builtin_nontemporal_store(o, &out4[i]);
    }
}

extern "C" void kernel_launch(void* const* d_in, const int* in_sizes, int n_in,
                              void* d_out, int out_size, void* d_ws, size_t ws_size,
                              hipStream_t stream) {
    const float* x     = (const float*)d_in[0];
    const float* w1    = (const float*)d_in[1];
    const float* w2    = (const float*)d_in[2];
    const float* sw    = (const float*)d_in[3];
    const float* sbias = (const float*)d_in[4];
    const float* alpha = (const float*)d_in[5];
    const float* beta  = (const float*)d_in[6];
    float* out = (float*)d_out;

    float* ws = (float*)d_ws;
    // workspace layout (floats):
    float* part_c  = ws;                                      // PBLKS*NCHUNK*4*CCHUNK = 204800
    float* part_s  = part_c + (size_t)PBLKS*NCHUNK*4*CCHUNK;  // NCHUNK*B*4*HW = 6553600
    float* s_in    = part_s + (size_t)NCHUNK*B*4*HW;          // B*4*HW = 819200
    float* sfac    = s_in   + (size_t)B*4*HW;                 // B*HW   = 204800
    float* chanfac = sfac   + (size_t)B*HW;                   // B*C    = 2048
    // total = 7,784,448 floats ~= 31.1 MB

    k1_sobel_stats<<<PBLKS*NCHUNK, 256, 0, stream>>>(x, part_c, part_s);

    void* args[] = {
        (void*)&x, (void*)&part_s, (void*)&part_c, (void*)&w1, (void*)&w2,
        (void*)&beta, (void*)&sw, (void*)&sbias, (void*)&alpha,
        (void*)&s_in, (void*)&sfac, (void*)&chanfac, (void*)&out
    };
    hipError_t err = hipLaunchCooperativeKernel((const void*)k_rest,
                                                dim3(GRIDB), dim3(256),
                                                args, 0, stream);
    if (err != hipSuccess) {
        // fallback: classic 3-launch chain
        k1b_fold_mlp<<<FOLDU + B,  256, 0, stream>>>(part_s, s_in, part_c, w1, w2, beta, chanfac);
        k3_spatial  <<<K3U,        256, 0, stream>>>(s_in, sw, sbias, alpha, sfac);
        k4_combine  <<<TOTF4/512,  256, 0, stream>>>(x, sfac, chanfac, out);
    }
}

// Round 8
// 461.359 us; speedup vs baseline: 1.4125x; 1.4125x over previous
//
#include <hip/hip_runtime.h>
#include <math.h>

#define B 8
#define C 256
#define H 160
#define W 160
#define HW (H*W)
#define HIDDEN 16

#define CCHUNK 32               // channels per k1 block
#define NCHUNK (C/CCHUNK)       // 8 channel chunks
#define GRP 4                   // channels per butterfly batch (reg-pressure cap)
#define W4 (W/4)                // 40 float4 per row
#define F4B (HW/4)              // 6400 float4 per (b,c) plane
#define PBB (F4B/256)           // 25 pixel-blocks per batch
#define PBLKS (B*PBB)           // 200 pixel-blocks total
#define FOLDU ((B*4*F4B)/256)   // 800 fold units
#define K3U   ((B*F4B)/64)      // 800 conv blocks (64 thr, 4px/thread)
#define TOTF4 (B*C*HW/4)        // 13,107,200 float4 in x/out

typedef float vf4 __attribute__((ext_vector_type(4)));

// Separable Sobel, packed-math friendly: S = t+2m+b and D = t-b are computed
// as vf4 vector ops (clang lowers to v_pk_fma/add_f32 on gfx950 — dual fp32).
// Misaligned u/v/sqrt stay scalar (no shuffle cost). 0.25 scale DEFERRED:
// returns/accumulates unscaled g; caller scales sum_g/max_g/part_c stores.
__device__ __forceinline__ float sobel4_vec(
    float tl, vf4 t4, float tr,
    float ml, vf4 m4, float mr,
    float bl, vf4 b4, float br,
    vf4& sum_x, vf4& max_x, vf4& sum_g, vf4& max_g)
{
    vf4 S = t4 + 2.f*m4 + b4;      // cols 1..4 smooth
    vf4 D = t4 - b4;               // cols 1..4 diff
    float sl = fmaf(2.f, ml, tl) + bl;
    float sr = fmaf(2.f, mr, tr) + br;
    float dl = tl - bl, dr = tr - br;

    float g0, g1, g2, g3;
    { float u = sl  - S.y, v = fmaf(2.f, D.x, dl)  + D.y;
      g0 = __builtin_amdgcn_sqrtf(fmaf(v, v, fmaf(u, u, 1.6e-11f))); }
    { float u = S.x - S.z, v = fmaf(2.f, D.y, D.x) + D.z;
      g1 = __builtin_amdgcn_sqrtf(fmaf(v, v, fmaf(u, u, 1.6e-11f))); }
    { float u = S.y - S.w, v = fmaf(2.f, D.z, D.y) + D.w;
      g2 = __builtin_amdgcn_sqrtf(fmaf(v, v, fmaf(u, u, 1.6e-11f))); }
    { float u = S.z - sr,  v = fmaf(2.f, D.w, D.z) + dr;
      g3 = __builtin_amdgcn_sqrtf(fmaf(v, v, fmaf(u, u, 1.6e-11f))); }

    sum_x += m4;
    max_x = __builtin_elementwise_max(max_x, m4);
    vf4 G = { g0, g1, g2, g3 };
    sum_g += G;
    max_g = __builtin_elementwise_max(max_g, G);
    return (g0+g1) + (g2+g3);
}

// ---------------- k1: Sobel + partial reductions, 4 px/thread ----------------
// 256-thread blocks, no min-wave forcing (R5 lesson). Wave-uniform fast path
// for row-interior waves; edge-path safety argument as R6.
__global__ __launch_bounds__(256) void k1_sobel_stats(
    const float* __restrict__ x, float* __restrict__ part_c,
    float* __restrict__ part_s)
{
    const int tid   = threadIdx.x;
    const int blk   = blockIdx.x;
    const int chunk = blk & (NCHUNK-1);
    const int pblk  = blk >> 3;                 // [0, PBLKS)
    const int f     = pblk * 256 + tid;         // global float4 index
    const int b     = f / F4B;
    const int r     = f % F4B;
    const int h     = r / W4;
    const int w     = (r % W4) * 4;             // leftmost of 4 pixels
    const int hw    = h * W + w;

    const bool up = (h > 0), dn = (h < H-1), lf = (w > 0), rt = (w+4 < W);
    const float lff = lf ? 1.f : 0.f, rtf = rt ? 1.f : 0.f;

    const float* xp = x + (size_t)(b*C + chunk*CCHUNK) * HW + hw;
    float* pcw = part_c + ((size_t)blk*4 + (tid >> 6)) * CCHUNK;

    vf4 sum_x = {0,0,0,0}, sum_g = {0,0,0,0};
    vf4 max_x = {-INFINITY,-INFINITY,-INFINITY,-INFINITY};
    vf4 max_g = {-INFINITY,-INFINITY,-INFINITY,-INFINITY};

    if (__all(up && dn)) {
        // -------- fast path: all lanes h in [1, H-2] --------
        #pragma unroll 1
        for (int grp = 0; grp < CCHUNK/GRP; ++grp) {
            float gs[GRP];
            #pragma unroll
            for (int u = 0; u < GRP; ++u) {
                const float* q = xp + (size_t)(grp*GRP + u) * HW;
                vf4 t4 = *(const vf4*)(q - W);
                vf4 m4 = *(const vf4*)(q);
                vf4 b4 = *(const vf4*)(q + W);
                float tl = q[-W-1]*lff, tr = q[-W+4]*rtf;
                float ml = q[-1]  *lff, mr = q[4]   *rtf;
                float bl = q[W-1] *lff, br = q[W+4] *rtf;
                gs[u] = sobel4_vec(tl,t4,tr, ml,m4,mr, bl,b4,br,
                                   sum_x, max_x, sum_g, max_g);
            }
            #pragma unroll
            for (int off = 32; off; off >>= 1) {
                #pragma unroll
                for (int u = 0; u < GRP; ++u)
                    gs[u] += __shfl_xor(gs[u], off, 64);
            }
            if ((tid & 63) == 0) {
                // 0.25 Sobel scale applied here (deferred from core)
                float4 v0 = { 0.25f*gs[0], 0.25f*gs[1], 0.25f*gs[2], 0.25f*gs[3] };
                *(float4*)(pcw + grp*GRP) = v0;
            }
        }
    } else {
        // -------- edge path: full masking + clamped offsets --------
        const float upf = up ? 1.f : 0.f, dnf = dn ? 1.f : 0.f;
        const float f_tl = upf*lff, f_tr = upf*rtf;
        const float f_bl = dnf*lff, f_br = dnf*rtf;
        const int ot = up ? -W : 0;
        const int ob = dn ?  W : 0;
        const int ol = lf ? -1 : 0;
        const int orr= rt ?  4 : 3;

        #pragma unroll 1
        for (int grp = 0; grp < CCHUNK/GRP; ++grp) {
            float gs[GRP];
            #pragma unroll
            for (int u = 0; u < GRP; ++u) {
                const float* q = xp + (size_t)(grp*GRP + u) * HW;
                vf4 t4 = (*(const vf4*)(q + ot)) * upf;
                vf4 m4 = *(const vf4*)(q);
                vf4 b4 = (*(const vf4*)(q + ob)) * dnf;
                float tl = q[ot+ol]*f_tl, tr = q[ot+orr]*f_tr;
                float ml = q[ol]  *lff,   mr = q[orr]  *rtf;
                float bl = q[ob+ol]*f_bl, br = q[ob+orr]*f_br;
                gs[u] = sobel4_vec(tl,t4,tr, ml,m4,mr, bl,b4,br,
                                   sum_x, max_x, sum_g, max_g);
            }
            #pragma unroll
            for (int off = 32; off; off >>= 1) {
                #pragma unroll
                for (int u = 0; u < GRP; ++u)
                    gs[u] += __shfl_xor(gs[u], off, 64);
            }
            if ((tid & 63) == 0) {
                float4 v0 = { 0.25f*gs[0], 0.25f*gs[1], 0.25f*gs[2], 0.25f*gs[3] };
                *(float4*)(pcw + grp*GRP) = v0;
            }
        }
    }

    float* sp = part_s + (size_t)(chunk*B + b) * 4 * HW + hw;
    *(vf4*)(sp)        = sum_x;
    *(vf4*)(sp +   HW) = max_x;
    *(vf4*)(sp + 2*HW) = sum_g * 0.25f;   // deferred Sobel scale
    *(vf4*)(sp + 3*HW) = max_g * 0.25f;
}

// ---------------- helpers ----------------
__device__ __forceinline__ void fold_unit(int u, int tid,
    const float* __restrict__ part_s, float* __restrict__ s_in)
{
    const int g    = u * 256 + tid;              // [0, B*4*F4B)
    const int b    = g / (4*F4B);
    const int rr   = g % (4*F4B);
    const int plane= rr / F4B;
    const int hw   = (rr % F4B) * 4;

    const float* sp0 = part_s + (size_t)b * 4 * HW + plane*HW + hw;
    const size_t cstride = (size_t)B * 4 * HW;

    vf4 v = *(const vf4*)(sp0);
    if (plane == 0 || plane == 2) {
        #pragma unroll
        for (int c = 1; c < NCHUNK; ++c)
            v += *(const vf4*)(sp0 + c*cstride);
        v *= (1.f/C);
    } else {
        #pragma unroll
        for (int c = 1; c < NCHUNK; ++c)
            v = __builtin_elementwise_max(v, *(const vf4*)(sp0 + c*cstride));
    }
    *(vf4*)(s_in + (size_t)b * 4 * HW + plane*HW + hw) = v;
}

__device__ __forceinline__ void mlp_block(int b, int tid,
    const float* __restrict__ part_c, const float* __restrict__ w1,
    const float* __restrict__ w2, const float* __restrict__ beta,
    float* __restrict__ chanfac, float* cv, float* hb)
{
    const int chunk = tid >> 5;            // CCHUNK=32
    const int cc    = tid & (CCHUNK-1);

    float acc = 0.f;
    for (int pbb = 0; pbb < PBB; ++pbb) {
        const int blk = (b*PBB + pbb) * NCHUNK + chunk;
        const float* pcb = part_c + (size_t)blk * 4 * CCHUNK + cc;
        acc += (pcb[0] + pcb[CCHUNK]) + (pcb[2*CCHUNK] + pcb[3*CCHUNK]);
    }
    cv[tid] = acc * (1.f/(float)HW);
    __syncthreads();

    if (tid < HIDDEN) {
        float a = 0.f;
        for (int c = 0; c < C; ++c) a += cv[c] * w1[tid*C + c];
        hb[tid] = fmaxf(a, 0.f);
    }
    __syncthreads();

    float bt = beta[0];
    float sb = (bt > 20.f) ? bt : log1pf(expf(bt));   // softplus
    float a = 0.f;
    #pragma unroll
    for (int j = 0; j < HIDDEN; ++j) a += hb[j] * w2[tid*HIDDEN + j];
    float gate = 1.f / (1.f + expf(-a));
    chanfac[b*C + tid] = 1.f + sb * gate;
}

// ---------------- k1b: fold partials into s_in + channel-gate MLP ----------------
__global__ __launch_bounds__(256) void k1b_fold_mlp(
    const float* __restrict__ part_s, float* __restrict__ s_in,
    const float* __restrict__ part_c, const float* __restrict__ w1,
    const float* __restrict__ w2, const float* __restrict__ beta,
    float* __restrict__ chanfac)
{
    __shared__ float cv[C];
    __shared__ float hb[HIDDEN];
    const int tid = threadIdx.x;
    if (blockIdx.x < FOLDU) { fold_unit(blockIdx.x, tid, part_s, s_in); return; }
    mlp_block(blockIdx.x - FOLDU, tid, part_c, w1, w2, beta, chanfac, cv, hb);
}

// ---------------- k3: 7x7 spatial conv + sigmoid, 4 px/thread (64-thr) ----------------
__global__ __launch_bounds__(64) void k3_spatial(
    const float* __restrict__ s_in, const float* __restrict__ sw,
    const float* __restrict__ sbias, const float* __restrict__ alpha,
    float* __restrict__ sfac)
{
    __shared__ float wgt[4*49];
    const int tid = threadIdx.x;
    for (int k = tid; k < 196; k += 64) wgt[k] = sw[k];
    __syncthreads();

    const int p4 = blockIdx.x * 64 + tid;    // [0, B*F4B)
    const int b  = p4 / F4B;
    const int r  = p4 % F4B;
    const int h  = r / W4;
    const int w  = (r % W4) * 4;

    float wmk[11];                            // col masks for rb[1..10]
    #pragma unroll
    for (int k = 1; k <= 10; ++k) {
        int col = w - 4 + k;
        wmk[k] = (col >= 0 && col < W) ? 1.f : 0.f;
    }
    int hc[7]; float hm[7];
    #pragma unroll
    for (int i = 0; i < 7; ++i) {
        int hh = h + i - 3;
        hm[i] = (hh >= 0 && hh < H) ? 1.f : 0.f;
        hc[i] = min(max(hh, 0), H-1);
    }
    const int loff = (w >= 4)    ? -4 : 0;    // clamped: masked anyway at w==0
    const int roff = (w + 4 < W) ?  4 : 0;    // clamped: masked anyway at w==W-4

    const float* base = s_in + (size_t)b * 4 * HW + w;
    float a0=0.f, a1=0.f, a2=0.f, a3=0.f;
    #pragma unroll
    for (int ci = 0; ci < 4; ++ci) {
        const float* pl = base + ci*HW;
        #pragma unroll
        for (int i = 0; i < 7; ++i) {
            const float* rp = pl + hc[i]*W;
            float4 L  = *(const float4*)(rp + loff);
            float4 Mv = *(const float4*)(rp);
            float4 R  = *(const float4*)(rp + roff);
            float rb[12] = { L.x,L.y,L.z,L.w, Mv.x,Mv.y,Mv.z,Mv.w, R.x,R.y,R.z,R.w };
            #pragma unroll
            for (int k = 1; k <= 10; ++k) rb[k] *= wmk[k];
            const float* wr = wgt + ci*49 + i*7;
            float r0=0.f, r1=0.f, r2=0.f, r3=0.f;
            #pragma unroll
            for (int j = 0; j < 7; ++j) {
                float wj = wr[j];
                r0 = fmaf(wj, rb[j+1], r0);
                r1 = fmaf(wj, rb[j+2], r1);
                r2 = fmaf(wj, rb[j+3], r2);
                r3 = fmaf(wj, rb[j+4], r3);
            }
            a0 = fmaf(r0, hm[i], a0);
            a1 = fmaf(r1, hm[i], a1);
            a2 = fmaf(r2, hm[i], a2);
            a3 = fmaf(r3, hm[i], a3);
        }
    }
    float al = alpha[0];
    float sa = (al > 20.f) ? al : log1pf(expf(al));   // softplus
    float bias = sbias[0];
    float4 o;
    o.x = 1.f + sa / (1.f + expf(-(a0 + bias)));
    o.y = 1.f + sa / (1.f + expf(-(a1 + bias)));
    o.z = 1.f + sa / (1.f + expf(-(a2 + bias)));
    o.w = 1.f + sa / (1.f + expf(-(a3 + bias)));
    *(float4*)(sfac + (size_t)b * HW + h*W + w) = o;
}

// ---------------- k4: elementwise combine (2 x float4, nontemporal) ----------------
__global__ __launch_bounds__(256) void k4_combine(
    const float* __restrict__ x, const float* __restrict__ sfac,
    const float* __restrict__ chanfac, float* __restrict__ out)
{
    const vf4* x4 = (const vf4*)x;
    vf4* out4 = (vf4*)out;
    const int i0 = blockIdx.x * 512 + threadIdx.x;
    #pragma unroll
    for (int k = 0; k < 2; ++k) {
        const int i  = i0 + k*256;
        const int bc = i / (HW/4);
        const int hw = (i % (HW/4)) * 4;
        const int b  = bc >> 8;
        const float cf = chanfac[bc];
        const vf4 s = *(const vf4*)&sfac[b*HW + hw];
        vf4 xv = __builtin_nontemporal_load(&x4[i]);
        vf4 o = xv * s * cf;
        __builtin_nontemporal_store(o, &out4[i]);
    }
}

extern "C" void kernel_launch(void* const* d_in, const int* in_sizes, int n_in,
                              void* d_out, int out_size, void* d_ws, size_t ws_size,
                              hipStream_t stream) {
    const float* x     = (const float*)d_in[0];
    const float* w1    = (const float*)d_in[1];
    const float* w2    = (const float*)d_in[2];
    const float* sw    = (const float*)d_in[3];
    const float* sbias = (const float*)d_in[4];
    const float* alpha = (const float*)d_in[5];
    const float* beta  = (const float*)d_in[6];
    float* out = (float*)d_out;

    float* ws = (float*)d_ws;
    // workspace layout (floats):
    float* part_c  = ws;                                      // PBLKS*NCHUNK*4*CCHUNK = 204800
    float* part_s  = part_c + (size_t)PBLKS*NCHUNK*4*CCHUNK;  // NCHUNK*B*4*HW = 6553600
    float* s_in    = part_s + (size_t)NCHUNK*B*4*HW;          // B*4*HW = 819200
    float* sfac    = s_in   + (size_t)B*4*HW;                 // B*HW   = 204800
    float* chanfac = sfac   + (size_t)B*HW;                   // B*C    = 2048
    // total = 7,784,448 floats ~= 31.1 MB

    k1_sobel_stats<<<PBLKS*NCHUNK, 256, 0, stream>>>(x, part_c, part_s);
    k1b_fold_mlp <<<FOLDU + B,  256, 0, stream>>>(part_s, s_in, part_c, w1, w2, beta, chanfac);
    k3_spatial   <<<K3U,        64,  0, stream>>>(s_in, sw, sbias, alpha, sfac);
    k4_combine   <<<TOTF4/512,  256, 0, stream>>>(x, sfac, chanfac, out);
}